// Round 3
// baseline (199.232 us; speedup 1.0000x reference)
//
#include <hip/hip_runtime.h>
#include <stdint.h>

typedef unsigned short u16;
typedef __attribute__((ext_vector_type(8))) __bf16 bf16x8;
typedef __attribute__((ext_vector_type(8))) short short8;
typedef __attribute__((ext_vector_type(4))) float f32x4;
typedef __attribute__((ext_vector_type(16))) float f32x16;
typedef __attribute__((ext_vector_type(4))) uint32_t u32x4;

#define AS1 __attribute__((address_space(1)))
#define AS3 __attribute__((address_space(3)))

__device__ __forceinline__ void load_lds16(const void* g, void* l) {
    __builtin_amdgcn_global_load_lds((AS1 void*)g, (AS3 void*)l, 16, 0, 0);
}

__device__ __forceinline__ u16 f2bf(float f) {
    uint32_t u = __builtin_bit_cast(uint32_t, f);
    u += 0x7FFFu + ((u >> 16) & 1u);
    return (u16)(u >> 16);
}

__device__ __forceinline__ f32x4 mfma16(bf16x8 a, bf16x8 b, f32x4 c) {
    return __builtin_amdgcn_mfma_f32_16x16x32_bf16(a, b, c, 0, 0, 0);
}
__device__ __forceinline__ f32x16 mfma32(bf16x8 a, bf16x8 b, f32x16 c) {
    return __builtin_amdgcn_mfma_f32_32x32x16_bf16(a, b, c, 0, 0, 0);
}

// balanced max over an f32x16 (depth 4; clang may fuse pairs into v_max3_f32)
__device__ __forceinline__ float max16(const f32x16& s) {
    const float t0 = fmaxf(s[0], s[1]),   t1 = fmaxf(s[2], s[3]);
    const float t2 = fmaxf(s[4], s[5]),   t3 = fmaxf(s[6], s[7]);
    const float t4 = fmaxf(s[8], s[9]),   t5 = fmaxf(s[10], s[11]);
    const float t6 = fmaxf(s[12], s[13]), t7 = fmaxf(s[14], s[15]);
    const float u0 = fmaxf(t0, t1), u1 = fmaxf(t2, t3);
    const float u2 = fmaxf(t4, t5), u3 = fmaxf(t6, t7);
    return fmaxf(fmaxf(u0, u1), fmaxf(u2, u3));
}

// ---------------------------------------------------------------- cast f32->bf16
__global__ __launch_bounds__(256) void cast_kernel(const float* __restrict__ src,
                                                   u16* __restrict__ dst, int n) {
    int i = (blockIdx.x * 256 + threadIdx.x) * 4;
    if (i < n) {
        const float4 v = *(const float4*)(src + i);
        u16 o0 = f2bf(v.x), o1 = f2bf(v.y), o2 = f2bf(v.z), o3 = f2bf(v.w);
        uint32_t lo = (uint32_t)o0 | ((uint32_t)o1 << 16);
        uint32_t hi = (uint32_t)o2 | ((uint32_t)o3 << 16);
        uint2 p; p.x = lo; p.y = hi;
        *(uint2*)(dst + i) = p;
    }
}

// ---------------------------------------------------------------- 128x128 GEMM core
template<int KDIM>
__device__ __forceinline__ void gemm_core(const u16* __restrict__ A, const u16* __restrict__ Bw,
                                          int m0, int n0, char* lds, f32x4 acc[4][4]) {
    const int tid = threadIdx.x;
    const int w = tid >> 6, l = tid & 63;
    const int lg = l >> 4, lc = l & 15;
    const int wm = (w >> 1) * 64, wn = (w & 1) * 64;
    char* As = lds;
    char* Bs = lds + 16384;
    for (int kt = 0; kt < KDIM; kt += 64) {
#pragma unroll
        for (int i = 0; i < 4; ++i) {
            const int e = i * 256 + tid;
            const int row = e >> 3, c = e & 7;
            const int cs = c ^ (row & 7);
            load_lds16(A + (size_t)(m0 + row) * KDIM + kt + cs * 8, As + i * 4096 + w * 1024);
            load_lds16(Bw + (size_t)(n0 + row) * KDIM + kt + cs * 8, Bs + i * 4096 + w * 1024);
        }
        __syncthreads();
#pragma unroll
        for (int kk = 0; kk < 2; ++kk) {
            bf16x8 af[4], bfr[4];
            const int byo = kk * 64 + lg * 16;
#pragma unroll
            for (int mi = 0; mi < 4; ++mi) {
                const int row = wm + mi * 16 + lc;
                af[mi] = *(const bf16x8*)(As + row * 128 + (byo ^ ((row & 7) << 4)));
            }
#pragma unroll
            for (int ni = 0; ni < 4; ++ni) {
                const int row = wn + ni * 16 + lc;
                bfr[ni] = *(const bf16x8*)(Bs + row * 128 + (byo ^ ((row & 7) << 4)));
            }
#pragma unroll
            for (int mi = 0; mi < 4; ++mi)
#pragma unroll
                for (int ni = 0; ni < 4; ++ni)
                    acc[mi][ni] = mfma16(af[mi], bfr[ni], acc[mi][ni]);
        }
        __syncthreads();
    }
}

// ---------------------------------------------------------------- fused QKV projection
// Q,K -> (B,H,T,D). V -> TRANSPOSED (B,H,D,T) so attn can stage it via
// global_load_lds with no register transpose. V writes vectorized 8B (4 consec t).
__global__ __launch_bounds__(256) void qkv_gemm(const u16* __restrict__ xb, const u16* __restrict__ wqkv,
                                                const float* __restrict__ bq, const float* __restrict__ bk,
                                                const float* __restrict__ bv,
                                                u16* __restrict__ qo, u16* __restrict__ ko, u16* __restrict__ vt) {
    __shared__ char lds[32768];
    f32x4 acc[4][4] = {};
    const int id = blockIdx.x;
    const int xcd = id & 7, sl = id >> 3;
    const int nIdx = sl >> 3, mloc = sl & 7;
    const int m0 = (xcd * 8 + mloc) * 128;
    const int n0 = nIdx * 128;
    gemm_core<1024>(xb, wqkv, m0, n0, lds, acc);
    const int which = n0 >> 10;
    const float* bias = which == 0 ? bq : (which == 1 ? bk : bv);
    const int tid = threadIdx.x;
    const int w = tid >> 6, l = tid & 63;
    const int lg = l >> 4, lc = l & 15;
    const int wm = (w >> 1) * 64, wn = (w & 1) * 64;
    if (which == 2) {
        // V: transposed store. t0 = m0+wm+mi*16+lg*4, 4 consecutive t per (mi,ni).
#pragma unroll
        for (int mi = 0; mi < 4; ++mi)
#pragma unroll
            for (int ni = 0; ni < 4; ++ni) {
                const int ng = n0 + wn + ni * 16 + lc;
                const int c = ng & 1023;
                const int h = c >> 6, d = c & 63;
                const float bb = bias[c];
                const int t0 = m0 + wm + mi * 16 + lg * 4;
                const int b = t0 >> 11, t = t0 & 2047;
                uint32_t w0 = (uint32_t)f2bf(acc[mi][ni][0] + bb) | ((uint32_t)f2bf(acc[mi][ni][1] + bb) << 16);
                uint32_t w1 = (uint32_t)f2bf(acc[mi][ni][2] + bb) | ((uint32_t)f2bf(acc[mi][ni][3] + bb) << 16);
                uint2 pk; pk.x = w0; pk.y = w1;
                *(uint2*)(vt + (((size_t)(b * 16 + h)) * 64 + d) * 2048 + t) = pk;
            }
    } else {
        u16* outb = which == 0 ? qo : ko;
#pragma unroll
        for (int mi = 0; mi < 4; ++mi)
#pragma unroll
            for (int ni = 0; ni < 4; ++ni)
#pragma unroll
                for (int r = 0; r < 4; ++r) {
                    const int m = m0 + wm + mi * 16 + lg * 4 + r;
                    const int ng = n0 + wn + ni * 16 + lc;
                    const int c = ng & 1023;
                    const float v = acc[mi][ni][r] + bias[c];
                    const int h = c >> 6, d = c & 63;
                    const int b = m >> 11, t = m & 2047;
                    outb[(((size_t)(b * 16 + h)) * 2048 + t) * 64 + d] = f2bf(v);
                }
    }
}

// ---------------------------------------------------------------- flash attention (causal)
// 32x32 swapped-QK^T (r0-verified compute & shuffle paths). One block = one
// 128-row q-strip, all 4 waves on it. CU-BALANCED placement:
// strip = (slot&15) ^ mask[slot>>5].
// r3: merged 64-s softmax per tile (one max-reduce / defer-vote / lrun update
// instead of two) + balanced max tree (depth 15 -> 4). All cross-lane exchange
// via r0-verified __shfl_xor; no permlane (2 failed rounds -- semantics
// ambiguity H1/H2 documented in journal, deferred).
#define CLOG 0.18033688f   /* 0.125 * log2(e) */

#define DEFER_RESCALE(TM)                                                       \
    {                                                                           \
        const float tmL = (TM) * CLOG;                                          \
        if (!__all(tmL <= mrun + 9.0f)) {                                       \
            const float mnew = fmaxf(mrun, tmL);                                \
            const float corr = exp2f(mrun - mnew);                              \
            mrun = mnew;                                                        \
            lrun *= corr;                                                       \
            _Pragma("unroll")                                                   \
            for (int rq = 0; rq < 4; ++rq)                                      \
                _Pragma("unroll")                                               \
                for (int rr = 0; rr < 4; ++rr) {                                \
                    const int q = rr + 8 * rq + 4 * hi;                         \
                    const float cb = __shfl(corr, q | (l & 32), 64);            \
                    oacc[0][rq * 4 + rr] *= cb;                                 \
                    oacc[1][rq * 4 + rr] *= cb;                                 \
                }                                                               \
        }                                                                       \
    }

// PV step for one 32-wide k-slot group (r0-verified shuffle/select build).
#define PVSTEP(W, KL, KS)                                                       \
    {                                                                           \
        const uint32_t wa = W[4 * (KL) + 0], wb_ = W[4 * (KL) + 1];             \
        const uint32_t wc = W[4 * (KL) + 2], wd = W[4 * (KL) + 3];              \
        const uint32_t xa = (uint32_t)__shfl_xor((int)wa, 32, 64);              \
        const uint32_t xb = (uint32_t)__shfl_xor((int)wb_, 32, 64);             \
        const uint32_t xc = (uint32_t)__shfl_xor((int)wc, 32, 64);              \
        const uint32_t xd = (uint32_t)__shfl_xor((int)wd, 32, 64);              \
        u32x4 pw;                                                               \
        pw[0] = hi ? xc : wa;                                                   \
        pw[1] = hi ? xd : wb_;                                                  \
        pw[2] = hi ? wc : xa;                                                   \
        pw[3] = hi ? wd : xb;                                                   \
        const bf16x8 paf = __builtin_bit_cast(bf16x8, pw);                      \
        __builtin_amdgcn_s_setprio(1);                                          \
        _Pragma("unroll")                                                       \
        for (int nb = 0; nb < 2; ++nb) {                                        \
            const int vrow = nb * 32 + l31;                                     \
            const bf16x8 bvf = *(const bf16x8*)(Vt + vrow * 128 +               \
                (((KS) * 32 + hi * 16) ^ ((vrow & 7) << 4)));                   \
            oacc[nb] = mfma32(paf, bvf, oacc[nb]);                              \
        }                                                                       \
        __builtin_amdgcn_s_setprio(0);                                          \
    }

__global__ __launch_bounds__(256) __attribute__((amdgpu_waves_per_eu(4, 4)))
void attn_kernel(const u16* __restrict__ qbuf, const u16* __restrict__ kbuf,
                 const u16* __restrict__ vtb, u16* __restrict__ attb) {
    __shared__ char lds[32768];  // [parity][ K 8KB | Vt 8KB ]: K rows [64 s][128B swz],
                                 // Vt rows [64 d][128B swz] (d-major, t within row)
    const int tid = threadIdx.x;
    const int w = tid >> 6, l = tid & 63;
    const int l31 = l & 31, hi = l >> 5;
    const int id = blockIdx.x;
    const int xcd = id & 7, slot = id >> 3;
    const int bh = xcd * 8 + (slot >> 4);        // 8 heads/XCD
    const int sl4 = slot & 15;
    const int kq = slot >> 5;                    // CU-round index, 0..3
    const int mask4[4] = {0, 15, 5, 10};
    const int strip = sl4 ^ mask4[kq];           // per-CU quadruple sums to 30
    const size_t base = (size_t)bh * 2048 * 64;  // same stride for (B,H,T,D)/(B,H,D,T)
    const int qw0 = strip * 128 + w * 32;        // this wave's 32 q rows
    const int jmax = (qw0 + 31) >> 6;            // last KV tile this wave needs
    const int tH = 2 * strip + 2;                // tiles staged by the block
    const int qg = qw0 + l31;

    // Q B-fragments: lane holds q=qw0+l31, d=16t+8hi+j
    bf16x8 aqf[4];
#pragma unroll
    for (int t = 0; t < 4; ++t)
        aqf[t] = *(const bf16x8*)(qbuf + base + (size_t)(qw0 + l31) * 64 + t * 16 + hi * 8);

    f32x16 oacc[2];
#pragma unroll
    for (int i = 0; i < 16; ++i) { oacc[0][i] = 0.f; oacc[1][i] = 0.f; }
    float mrun = -3.0e38f, lrun = 0.f;

    // K tile j: rows s=j*64+row (row 0..63), 8x16B chunks, pre-swizzled source.
#define ISSUE_K(J, BUF)                                                                          \
    {                                                                                            \
        _Pragma("unroll")                                                                        \
        for (int i = 0; i < 2; ++i) {                                                            \
            const int e = i * 256 + tid;                                                         \
            const int row = e >> 3, c = e & 7;                                                   \
            const int cs = c ^ (row & 7);                                                        \
            load_lds16(kbuf + base + (size_t)((J) * 64 + row) * 64 + cs * 8,                     \
                       (BUF) + i * 4096 + w * 1024);                                             \
        }                                                                                        \
    }
    // Vt tile j: rows d=row (0..63), t-span j*64..j*64+63, pre-swizzled source.
#define ISSUE_VT(J, BUF)                                                                         \
    {                                                                                            \
        _Pragma("unroll")                                                                        \
        for (int i = 0; i < 2; ++i) {                                                            \
            const int e = i * 256 + tid;                                                         \
            const int row = e >> 3, c = e & 7;                                                   \
            const int cs = c ^ (row & 7);                                                        \
            load_lds16(vtb + base + (size_t)row * 2048 + (J) * 64 + cs * 8,                      \
                       (BUF) + i * 4096 + w * 1024);                                             \
        }                                                                                        \
    }

    ISSUE_K(0, lds);
    ISSUE_VT(0, lds + 8192);
    for (int j = 0; j < tH; ++j) {
        __syncthreads();   // drains tile-j loads; protects buffers from prior compute
        if (j + 1 < tH) {
            char* nb2 = lds + ((j + 1) & 1) * 16384;
            ISSUE_K(j + 1, nb2);
            ISSUE_VT(j + 1, nb2 + 8192);
        }
        if (j <= jmax) {
            char* Ks = lds + (j & 1) * 16384;
            char* Vt = Ks + 8192;
            const bool two = (qw0 >= j * 64 + 32);   // wave-uniform: upper 32-s block live?
            // ---- S^T = K Q^T, lower 32-s half
            f32x16 sf0;
#pragma unroll
            for (int i = 0; i < 16; ++i) sf0[i] = 0.f;
            __builtin_amdgcn_s_setprio(1);
#pragma unroll
            for (int t = 0; t < 4; ++t) {
                const bf16x8 ak = *(const bf16x8*)(Ks + l31 * 128 + ((t * 32 + hi * 16) ^ ((l31 & 7) << 4)));
                sf0 = mfma32(ak, aqf[t], sf0);
            }
            __builtin_amdgcn_s_setprio(0);
            if (two) {
                // ---- upper 32-s half
                f32x16 sf1;
#pragma unroll
                for (int i = 0; i < 16; ++i) sf1[i] = 0.f;
                __builtin_amdgcn_s_setprio(1);
#pragma unroll
                for (int t = 0; t < 4; ++t) {
                    const int row = 32 + l31;
                    const bf16x8 ak = *(const bf16x8*)(Ks + row * 128 + ((t * 32 + hi * 16) ^ ((row & 7) << 4)));
                    sf1 = mfma32(ak, aqf[t], sf1);
                }
                __builtin_amdgcn_s_setprio(0);
                // causal mask: lower half fully unmasked when `two`; upper half
                // straddles the diagonal only when qw0 == j*64+32.
                if (qw0 == j * 64 + 32) {
#pragma unroll
                    for (int rg = 0; rg < 16; ++rg) {
                        const int ss = j * 64 + 32 + (rg & 3) + 8 * (rg >> 2) + 4 * hi;
                        if (ss > qg) sf1[rg] = -3.0e38f;
                    }
                }
                // ---- merged row max over 64 s (balanced tree, then cross-half)
                float tm = fmaxf(max16(sf0), max16(sf1));
                tm = fmaxf(tm, __shfl_xor(tm, 32, 64));
                DEFER_RESCALE(tm);
                // ---- P = exp2(raw*CLOG - mrun), row sum (two parallel chains)
                float rs0 = 0.f, rs1 = 0.f;
#pragma unroll
                for (int rg = 0; rg < 16; ++rg) {
                    const float p = exp2f(fmaf(sf0[rg], CLOG, -mrun));
                    sf0[rg] = p; rs0 += p;
                }
#pragma unroll
                for (int rg = 0; rg < 16; ++rg) {
                    const float p = exp2f(fmaf(sf1[rg], CLOG, -mrun));
                    sf1[rg] = p; rs1 += p;
                }
                float rs = rs0 + rs1;
                rs += __shfl_xor(rs, 32, 64);
                lrun += rs;
                // ---- pack P pairs: wv[i] = {rg=2i lo, rg=2i+1 hi}
                uint32_t wv0[8], wv1[8];
#pragma unroll
                for (int i = 0; i < 8; ++i) {
                    uint32_t wwa, wwb;
                    asm("v_cvt_pk_bf16_f32 %0, %1, %2" : "=v"(wwa) : "v"(sf0[2 * i]), "v"(sf0[2 * i + 1]));
                    asm("v_cvt_pk_bf16_f32 %0, %1, %2" : "=v"(wwb) : "v"(sf1[2 * i]), "v"(sf1[2 * i + 1]));
                    wv0[i] = wwa;
                    wv1[i] = wwb;
                }
                // ---- PV: ks = b2*2+kl
                PVSTEP(wv0, 0, 0)
                PVSTEP(wv0, 1, 1)
                PVSTEP(wv1, 0, 2)
                PVSTEP(wv1, 1, 3)
            } else {
                // diagonal half-tile (qw0 == j*64): lower 32 s only, always masked
#pragma unroll
                for (int rg = 0; rg < 16; ++rg) {
                    const int ss = j * 64 + (rg & 3) + 8 * (rg >> 2) + 4 * hi;
                    if (ss > qg) sf0[rg] = -3.0e38f;
                }
                float tm = max16(sf0);
                tm = fmaxf(tm, __shfl_xor(tm, 32, 64));
                DEFER_RESCALE(tm);
                float rs0 = 0.f;
#pragma unroll
                for (int rg = 0; rg < 16; ++rg) {
                    const float p = exp2f(fmaf(sf0[rg], CLOG, -mrun));
                    sf0[rg] = p; rs0 += p;
                }
                rs0 += __shfl_xor(rs0, 32, 64);
                lrun += rs0;
                uint32_t wv0[8];
#pragma unroll
                for (int i = 0; i < 8; ++i) {
                    uint32_t ww;
                    asm("v_cvt_pk_bf16_f32 %0, %1, %2" : "=v"(ww) : "v"(sf0[2 * i]), "v"(sf0[2 * i + 1]));
                    wv0[i] = ww;
                }
                PVSTEP(wv0, 0, 0)
                PVSTEP(wv0, 1, 1)
            }
        }
    }
    // ---- epilogue: normalize, write (B,T,C) bf16
    const int b = bh >> 4, h = bh & 15;
    const float inv = 1.f / lrun;
#pragma unroll
    for (int rq = 0; rq < 4; ++rq)
#pragma unroll
        for (int rr = 0; rr < 4; ++rr) {
            const int q = rr + 8 * rq + 4 * hi;
            const float iv = __shfl(inv, q | (l & 32), 64);
            const int t = qw0 + q;
#pragma unroll
            for (int nb = 0; nb < 2; ++nb) {
                const int c = h * 64 + nb * 32 + l31;
                attb[((size_t)(b * 2048 + t)) * 1024 + c] = f2bf(oacc[nb][rq * 4 + rr] * iv);
            }
        }
}

// ---------------------------------------------------------------- output projection (fp32 out)
__global__ __launch_bounds__(256) void proj_gemm(const u16* __restrict__ attb, const u16* __restrict__ wpb,
                                                 const float* __restrict__ bp, float* __restrict__ out) {
    __shared__ char lds[32768];
    f32x4 acc[4][4] = {};
    const int id = blockIdx.x;
    const int xcd = id & 7, sl = id >> 3;
    const int nIdx = sl >> 3, mloc = sl & 7;
    const int m0 = (xcd * 8 + mloc) * 128;
    const int n0 = nIdx * 128;
    gemm_core<1024>(attb, wpb, m0, n0, lds, acc);
    const int tid = threadIdx.x;
    const int w = tid >> 6, l = tid & 63;
    const int lg = l >> 4, lc = l & 15;
    const int wm = (w >> 1) * 64, wn = (w & 1) * 64;
#pragma unroll
    for (int mi = 0; mi < 4; ++mi)
#pragma unroll
        for (int ni = 0; ni < 4; ++ni)
#pragma unroll
            for (int r = 0; r < 4; ++r) {
                const int m = m0 + wm + mi * 16 + lg * 4 + r;
                const int n = n0 + wn + ni * 16 + lc;
                out[(size_t)m * 1024 + n] = acc[mi][ni][r] + bp[n];
            }
}

// ---------------------------------------------------------------- launch
extern "C" void kernel_launch(void* const* d_in, const int* in_sizes, int n_in,
                              void* d_out, int out_size, void* d_ws, size_t ws_size,
                              hipStream_t stream) {
    const float* x  = (const float*)d_in[0];
    const float* Wk = (const float*)d_in[1];
    const float* bk = (const float*)d_in[2];
    const float* Wq = (const float*)d_in[3];
    const float* bq = (const float*)d_in[4];
    const float* Wv = (const float*)d_in[5];
    const float* bv = (const float*)d_in[6];
    const float* Wp = (const float*)d_in[7];
    const float* bp = (const float*)d_in[8];
    char* ws = (char*)d_ws;
    u16* xb   = (u16*)(ws);
    u16* wqkv = (u16*)(ws + 16777216);
    u16* wpb  = (u16*)(ws + 23068672);
    u16* qbuf = (u16*)(ws + 25165824);
    u16* kbuf = (u16*)(ws + 41943040);
    u16* vtb  = (u16*)(ws + 58720256);   // (B,H,D,T) pre-transposed V
    u16* attb = (u16*)(ws + 75497472);

    cast_kernel<<<8192, 256, 0, stream>>>(x, xb, 8388608);
    cast_kernel<<<1024, 256, 0, stream>>>(Wq, wqkv,            1048576);
    cast_kernel<<<1024, 256, 0, stream>>>(Wk, wqkv + 1048576,  1048576);
    cast_kernel<<<1024, 256, 0, stream>>>(Wv, wqkv + 2097152,  1048576);
    cast_kernel<<<1024, 256, 0, stream>>>(Wp, wpb, 1048576);
    qkv_gemm<<<1536, 256, 0, stream>>>(xb, wqkv, bq, bk, bv, qbuf, kbuf, vtb);
    attn_kernel<<<1024, 256, 0, stream>>>(qbuf, kbuf, vtb, attb);
    proj_gemm<<<512, 256, 0, stream>>>(attb, wpb, bp, (float*)d_out);
}

// Round 4
// 188.046 us; speedup vs baseline: 1.0595x; 1.0595x over previous
//
#include <hip/hip_runtime.h>
#include <stdint.h>

typedef unsigned short u16;
typedef __attribute__((ext_vector_type(8))) __bf16 bf16x8;
typedef __attribute__((ext_vector_type(8))) short short8;
typedef __attribute__((ext_vector_type(4))) float f32x4;
typedef __attribute__((ext_vector_type(16))) float f32x16;
typedef __attribute__((ext_vector_type(4))) uint32_t u32x4;

#define AS1 __attribute__((address_space(1)))
#define AS3 __attribute__((address_space(3)))

__device__ __forceinline__ void load_lds16(const void* g, void* l) {
    __builtin_amdgcn_global_load_lds((AS1 void*)g, (AS3 void*)l, 16, 0, 0);
}

__device__ __forceinline__ u16 f2bf(float f) {
    uint32_t u = __builtin_bit_cast(uint32_t, f);
    u += 0x7FFFu + ((u >> 16) & 1u);
    return (u16)(u >> 16);
}

__device__ __forceinline__ f32x4 mfma16(bf16x8 a, bf16x8 b, f32x4 c) {
    return __builtin_amdgcn_mfma_f32_16x16x32_bf16(a, b, c, 0, 0, 0);
}
__device__ __forceinline__ f32x16 mfma32(bf16x8 a, bf16x8 b, f32x16 c) {
    return __builtin_amdgcn_mfma_f32_32x32x16_bf16(a, b, c, 0, 0, 0);
}

// balanced max over an f32x16 (depth 4 vs serial chain depth 15).
// Pressure-neutral: consumes the same 16 values, no extra live state.
__device__ __forceinline__ float max16(const f32x16& s) {
    const float t0 = fmaxf(s[0], s[1]),   t1 = fmaxf(s[2], s[3]);
    const float t2 = fmaxf(s[4], s[5]),   t3 = fmaxf(s[6], s[7]);
    const float t4 = fmaxf(s[8], s[9]),   t5 = fmaxf(s[10], s[11]);
    const float t6 = fmaxf(s[12], s[13]), t7 = fmaxf(s[14], s[15]);
    const float u0 = fmaxf(t0, t1), u1 = fmaxf(t2, t3);
    const float u2 = fmaxf(t4, t5), u3 = fmaxf(t6, t7);
    return fmaxf(fmaxf(u0, u1), fmaxf(u2, u3));
}

// ---------------------------------------------------------------- fused cast f32->bf16
// Single launch for x + 4 weight matrices (was 5 launches). All ranges are
// exact multiples of 1024 elems/block so no bounds checks needed.
__global__ __launch_bounds__(256) void cast_all(const float* __restrict__ x,
                                                const float* __restrict__ wq,
                                                const float* __restrict__ wk,
                                                const float* __restrict__ wv,
                                                const float* __restrict__ wp,
                                                u16* __restrict__ xb,
                                                u16* __restrict__ wqkv,
                                                u16* __restrict__ wpb) {
    const int bid = blockIdx.x;
    const float* src;
    u16* dst;
    int boff;
    if (bid < 8192)       { src = x;  dst = xb;             boff = bid; }
    else if (bid < 9216)  { src = wq; dst = wqkv;           boff = bid - 8192; }
    else if (bid < 10240) { src = wk; dst = wqkv + 1048576; boff = bid - 9216; }
    else if (bid < 11264) { src = wv; dst = wqkv + 2097152; boff = bid - 10240; }
    else                  { src = wp; dst = wpb;            boff = bid - 11264; }
    const int i = (boff * 256 + threadIdx.x) * 4;
    const float4 v = *(const float4*)(src + i);
    u16 o0 = f2bf(v.x), o1 = f2bf(v.y), o2 = f2bf(v.z), o3 = f2bf(v.w);
    uint32_t lo = (uint32_t)o0 | ((uint32_t)o1 << 16);
    uint32_t hi = (uint32_t)o2 | ((uint32_t)o3 << 16);
    uint2 p; p.x = lo; p.y = hi;
    *(uint2*)(dst + i) = p;
}

// ---------------------------------------------------------------- 128x128 GEMM core
template<int KDIM>
__device__ __forceinline__ void gemm_core(const u16* __restrict__ A, const u16* __restrict__ Bw,
                                          int m0, int n0, char* lds, f32x4 acc[4][4]) {
    const int tid = threadIdx.x;
    const int w = tid >> 6, l = tid & 63;
    const int lg = l >> 4, lc = l & 15;
    const int wm = (w >> 1) * 64, wn = (w & 1) * 64;
    char* As = lds;
    char* Bs = lds + 16384;
    for (int kt = 0; kt < KDIM; kt += 64) {
#pragma unroll
        for (int i = 0; i < 4; ++i) {
            const int e = i * 256 + tid;
            const int row = e >> 3, c = e & 7;
            const int cs = c ^ (row & 7);
            load_lds16(A + (size_t)(m0 + row) * KDIM + kt + cs * 8, As + i * 4096 + w * 1024);
            load_lds16(Bw + (size_t)(n0 + row) * KDIM + kt + cs * 8, Bs + i * 4096 + w * 1024);
        }
        __syncthreads();
#pragma unroll
        for (int kk = 0; kk < 2; ++kk) {
            bf16x8 af[4], bfr[4];
            const int byo = kk * 64 + lg * 16;
#pragma unroll
            for (int mi = 0; mi < 4; ++mi) {
                const int row = wm + mi * 16 + lc;
                af[mi] = *(const bf16x8*)(As + row * 128 + (byo ^ ((row & 7) << 4)));
            }
#pragma unroll
            for (int ni = 0; ni < 4; ++ni) {
                const int row = wn + ni * 16 + lc;
                bfr[ni] = *(const bf16x8*)(Bs + row * 128 + (byo ^ ((row & 7) << 4)));
            }
#pragma unroll
            for (int mi = 0; mi < 4; ++mi)
#pragma unroll
                for (int ni = 0; ni < 4; ++ni)
                    acc[mi][ni] = mfma16(af[mi], bfr[ni], acc[mi][ni]);
        }
        __syncthreads();
    }
}

// ---------------------------------------------------------------- fused QKV projection
// Q,K -> (B,H,T,D). V -> TRANSPOSED (B,H,D,T) so attn can stage it via
// global_load_lds with no register transpose. V writes vectorized 8B (4 consec t).
__global__ __launch_bounds__(256) void qkv_gemm(const u16* __restrict__ xb, const u16* __restrict__ wqkv,
                                                const float* __restrict__ bq, const float* __restrict__ bk,
                                                const float* __restrict__ bv,
                                                u16* __restrict__ qo, u16* __restrict__ ko, u16* __restrict__ vt) {
    __shared__ char lds[32768];
    f32x4 acc[4][4] = {};
    const int id = blockIdx.x;
    const int xcd = id & 7, sl = id >> 3;
    const int nIdx = sl >> 3, mloc = sl & 7;
    const int m0 = (xcd * 8 + mloc) * 128;
    const int n0 = nIdx * 128;
    gemm_core<1024>(xb, wqkv, m0, n0, lds, acc);
    const int which = n0 >> 10;
    const float* bias = which == 0 ? bq : (which == 1 ? bk : bv);
    const int tid = threadIdx.x;
    const int w = tid >> 6, l = tid & 63;
    const int lg = l >> 4, lc = l & 15;
    const int wm = (w >> 1) * 64, wn = (w & 1) * 64;
    if (which == 2) {
        // V: transposed store. t0 = m0+wm+mi*16+lg*4, 4 consecutive t per (mi,ni).
#pragma unroll
        for (int mi = 0; mi < 4; ++mi)
#pragma unroll
            for (int ni = 0; ni < 4; ++ni) {
                const int ng = n0 + wn + ni * 16 + lc;
                const int c = ng & 1023;
                const int h = c >> 6, d = c & 63;
                const float bb = bias[c];
                const int t0 = m0 + wm + mi * 16 + lg * 4;
                const int b = t0 >> 11, t = t0 & 2047;
                uint32_t w0 = (uint32_t)f2bf(acc[mi][ni][0] + bb) | ((uint32_t)f2bf(acc[mi][ni][1] + bb) << 16);
                uint32_t w1 = (uint32_t)f2bf(acc[mi][ni][2] + bb) | ((uint32_t)f2bf(acc[mi][ni][3] + bb) << 16);
                uint2 pk; pk.x = w0; pk.y = w1;
                *(uint2*)(vt + (((size_t)(b * 16 + h)) * 64 + d) * 2048 + t) = pk;
            }
    } else {
        u16* outb = which == 0 ? qo : ko;
#pragma unroll
        for (int mi = 0; mi < 4; ++mi)
#pragma unroll
            for (int ni = 0; ni < 4; ++ni)
#pragma unroll
                for (int r = 0; r < 4; ++r) {
                    const int m = m0 + wm + mi * 16 + lg * 4 + r;
                    const int ng = n0 + wn + ni * 16 + lc;
                    const int c = ng & 1023;
                    const float v = acc[mi][ni][r] + bias[c];
                    const int h = c >> 6, d = c & 63;
                    const int b = m >> 11, t = m & 2047;
                    outb[(((size_t)(b * 16 + h)) * 2048 + t) * 64 + d] = f2bf(v);
                }
    }
}

// ---------------------------------------------------------------- flash attention (causal)
// 32x32 swapped-QK^T (r0-verified compute & shuffle paths). One block = one
// 128-row q-strip, all 4 waves on it. CU-BALANCED placement: co-resident slots
// on a CU are {s,s+32,s+64,s+96}; strip = (slot&15) ^ mask[k] with mask
// {0,15,5,10} makes every CU's four strip durations sum to 68 tile-units.
// r4: EXACT r0 structure (per-32-block softmax -- merged version spilled to
// scratch, +8MB WRITE_SIZE, r3 post-mortem) with ONLY the pressure-neutral
// balanced max tree (depth 15 -> 4) added.
#define CLOG 0.18033688f   /* 0.125 * log2(e) */
__global__ __launch_bounds__(256) __attribute__((amdgpu_waves_per_eu(4, 4)))
void attn_kernel(const u16* __restrict__ qbuf, const u16* __restrict__ kbuf,
                 const u16* __restrict__ vtb, u16* __restrict__ attb) {
    __shared__ char lds[32768];  // [parity][ K 8KB | Vt 8KB ]: K rows [64 s][128B swz],
                                 // Vt rows [64 d][128B swz] (d-major, t within row)
    const int tid = threadIdx.x;
    const int w = tid >> 6, l = tid & 63;
    const int l31 = l & 31, hi = l >> 5;
    const int id = blockIdx.x;
    const int xcd = id & 7, slot = id >> 3;
    const int bh = xcd * 8 + (slot >> 4);        // 8 heads/XCD
    const int sl4 = slot & 15;
    const int kq = slot >> 5;                    // CU-round index, 0..3
    const int mask4[4] = {0, 15, 5, 10};
    const int strip = sl4 ^ mask4[kq];           // per-CU quadruple sums to 30
    const size_t base = (size_t)bh * 2048 * 64;  // same stride for (B,H,T,D)/(B,H,D,T)
    const int qw0 = strip * 128 + w * 32;        // this wave's 32 q rows
    const int jmax = (qw0 + 31) >> 6;            // last KV tile this wave needs
    const int tH = 2 * strip + 2;                // tiles staged by the block
    const int qg = qw0 + l31;

    // Q B-fragments: lane holds q=qw0+l31, d=16t+8hi+j
    bf16x8 aqf[4];
#pragma unroll
    for (int t = 0; t < 4; ++t)
        aqf[t] = *(const bf16x8*)(qbuf + base + (size_t)(qw0 + l31) * 64 + t * 16 + hi * 8);

    f32x16 oacc[2];
#pragma unroll
    for (int i = 0; i < 16; ++i) { oacc[0][i] = 0.f; oacc[1][i] = 0.f; }
    float mrun = -3.0e38f, lrun = 0.f;

    // K tile j: rows s=j*64+row (row 0..63), 8x16B chunks, pre-swizzled source.
#define ISSUE_K(J, BUF)                                                                          \
    {                                                                                            \
        _Pragma("unroll")                                                                        \
        for (int i = 0; i < 2; ++i) {                                                            \
            const int e = i * 256 + tid;                                                         \
            const int row = e >> 3, c = e & 7;                                                   \
            const int cs = c ^ (row & 7);                                                        \
            load_lds16(kbuf + base + (size_t)((J) * 64 + row) * 64 + cs * 8,                     \
                       (BUF) + i * 4096 + w * 1024);                                             \
        }                                                                                        \
    }
    // Vt tile j: rows d=row (0..63), t-span j*64..j*64+63, pre-swizzled source.
#define ISSUE_VT(J, BUF)                                                                         \
    {                                                                                            \
        _Pragma("unroll")                                                                        \
        for (int i = 0; i < 2; ++i) {                                                            \
            const int e = i * 256 + tid;                                                         \
            const int row = e >> 3, c = e & 7;                                                   \
            const int cs = c ^ (row & 7);                                                        \
            load_lds16(vtb + base + (size_t)row * 2048 + (J) * 64 + cs * 8,                      \
                       (BUF) + i * 4096 + w * 1024);                                             \
        }                                                                                        \
    }

    ISSUE_K(0, lds);
    ISSUE_VT(0, lds + 8192);
    for (int j = 0; j < tH; ++j) {
        __syncthreads();   // drains tile-j loads; protects buffers from prior compute
        if (j + 1 < tH) {
            char* nb2 = lds + ((j + 1) & 1) * 16384;
            ISSUE_K(j + 1, nb2);
            ISSUE_VT(j + 1, nb2 + 8192);
        }
        if (j <= jmax) {
            char* Ks = lds + (j & 1) * 16384;
            char* Vt = Ks + 8192;
#pragma unroll
            for (int b2 = 0; b2 < 2; ++b2) {
                const int S0b = j * 64 + b2 * 32;
                if (S0b > qw0 + 31) continue;           // fully masked (wave-uniform)
                const bool domask = (S0b + 31 > qw0);
                // ---- S^T = K Q^T for this 32-s block
                f32x16 sf;
#pragma unroll
                for (int i = 0; i < 16; ++i) sf[i] = 0.f;
                const int row = b2 * 32 + l31;
                __builtin_amdgcn_s_setprio(1);
#pragma unroll
                for (int t = 0; t < 4; ++t) {
                    const bf16x8 akf = *(const bf16x8*)(Ks + row * 128 + ((t * 32 + hi * 16) ^ ((row & 7) << 4)));
                    sf = mfma32(akf, aqf[t], sf);
                }
                __builtin_amdgcn_s_setprio(0);
                // ---- causal mask; s row = S0b + (rg&3)+8*(rg>>2)+4*hi
                if (domask) {
#pragma unroll
                    for (int rg = 0; rg < 16; ++rg) {
                        const int ss = S0b + (rg & 3) + 8 * (rg >> 2) + 4 * hi;
                        if (ss > qg) sf[rg] = -3.0e38f;
                    }
                }
                // ---- row max (balanced tree) + defer-max
                float tm = max16(sf);
                tm = fmaxf(tm, __shfl_xor(tm, 32, 64));
                const float tmL = tm * CLOG;
                if (!__all(tmL <= mrun + 9.0f)) {       // rare path
                    const float mnew = fmaxf(mrun, tmL);
                    const float corr = exp2f(mrun - mnew);
                    mrun = mnew;
                    lrun *= corr;
#pragma unroll
                    for (int rq = 0; rq < 4; ++rq)
#pragma unroll
                        for (int rr = 0; rr < 4; ++rr) {
                            const int q = rr + 8 * rq + 4 * hi;
                            const float cb = __shfl(corr, q | (l & 32), 64);
                            oacc[0][rq * 4 + rr] *= cb;
                            oacc[1][rq * 4 + rr] *= cb;
                        }
                }
                // ---- P = exp2(raw*CLOG - mrun), row sum
                float rs = 0.f;
#pragma unroll
                for (int rg = 0; rg < 16; ++rg) {
                    const float p = exp2f(fmaf(sf[rg], CLOG, -mrun));
                    sf[rg] = p;
                    rs += p;
                }
                rs += __shfl_xor(rs, 32, 64);
                lrun += rs;
                // ---- pack P pairs: wv[i] = {rg=2i lo, rg=2i+1 hi}
                uint32_t wv[8];
#pragma unroll
                for (int i = 0; i < 8; ++i) {
                    uint32_t ww;
                    asm("v_cvt_pk_bf16_f32 %0, %1, %2" : "=v"(ww) : "v"(sf[2 * i]), "v"(sf[2 * i + 1]));
                    wv[i] = ww;
                }
                // ---- per-ks A-fragment build + PV (r7-verified shuffle/select)
#pragma unroll
                for (int kl = 0; kl < 2; ++kl) {
                    const uint32_t wa = wv[4 * kl + 0], wb_ = wv[4 * kl + 1];
                    const uint32_t wc = wv[4 * kl + 2], wd = wv[4 * kl + 3];
                    const uint32_t xa = (uint32_t)__shfl_xor((int)wa, 32, 64);
                    const uint32_t xb = (uint32_t)__shfl_xor((int)wb_, 32, 64);
                    const uint32_t xc = (uint32_t)__shfl_xor((int)wc, 32, 64);
                    const uint32_t xd = (uint32_t)__shfl_xor((int)wd, 32, 64);
                    u32x4 pw;
                    pw[0] = hi ? xc : wa;
                    pw[1] = hi ? xd : wb_;
                    pw[2] = hi ? wc : xa;
                    pw[3] = hi ? wd : xb;
                    const bf16x8 paf = __builtin_bit_cast(bf16x8, pw);
                    const int ks = b2 * 2 + kl;
                    __builtin_amdgcn_s_setprio(1);
#pragma unroll
                    for (int nb = 0; nb < 2; ++nb) {
                        const int vrow = nb * 32 + l31;
                        const bf16x8 bvf = *(const bf16x8*)(Vt + vrow * 128 +
                            ((ks * 32 + hi * 16) ^ ((vrow & 7) << 4)));
                        oacc[nb] = mfma32(paf, bvf, oacc[nb]);
                    }
                    __builtin_amdgcn_s_setprio(0);
                }
            }
        }
    }
    // ---- epilogue: normalize, write (B,T,C) bf16
    const int b = bh >> 4, h = bh & 15;
    const float inv = 1.f / lrun;
#pragma unroll
    for (int rq = 0; rq < 4; ++rq)
#pragma unroll
        for (int rr = 0; rr < 4; ++rr) {
            const int q = rr + 8 * rq + 4 * hi;
            const float iv = __shfl(inv, q | (l & 32), 64);
            const int t = qw0 + q;
#pragma unroll
            for (int nb = 0; nb < 2; ++nb) {
                const int c = h * 64 + nb * 32 + l31;
                attb[((size_t)(b * 2048 + t)) * 1024 + c] = f2bf(oacc[nb][rq * 4 + rr] * iv);
            }
        }
}

// ---------------------------------------------------------------- output projection (fp32 out)
__global__ __launch_bounds__(256) void proj_gemm(const u16* __restrict__ attb, const u16* __restrict__ wpb,
                                                 const float* __restrict__ bp, float* __restrict__ out) {
    __shared__ char lds[32768];
    f32x4 acc[4][4] = {};
    const int id = blockIdx.x;
    const int xcd = id & 7, sl = id >> 3;
    const int nIdx = sl >> 3, mloc = sl & 7;
    const int m0 = (xcd * 8 + mloc) * 128;
    const int n0 = nIdx * 128;
    gemm_core<1024>(attb, wpb, m0, n0, lds, acc);
    const int tid = threadIdx.x;
    const int w = tid >> 6, l = tid & 63;
    const int lg = l >> 4, lc = l & 15;
    const int wm = (w >> 1) * 64, wn = (w & 1) * 64;
#pragma unroll
    for (int mi = 0; mi < 4; ++mi)
#pragma unroll
        for (int ni = 0; ni < 4; ++ni)
#pragma unroll
            for (int r = 0; r < 4; ++r) {
                const int m = m0 + wm + mi * 16 + lg * 4 + r;
                const int n = n0 + wn + ni * 16 + lc;
                out[(size_t)m * 1024 + n] = acc[mi][ni][r] + bp[n];
            }
}

// ---------------------------------------------------------------- launch
extern "C" void kernel_launch(void* const* d_in, const int* in_sizes, int n_in,
                              void* d_out, int out_size, void* d_ws, size_t ws_size,
                              hipStream_t stream) {
    const float* x  = (const float*)d_in[0];
    const float* Wk = (const float*)d_in[1];
    const float* bk = (const float*)d_in[2];
    const float* Wq = (const float*)d_in[3];
    const float* bq = (const float*)d_in[4];
    const float* Wv = (const float*)d_in[5];
    const float* bv = (const float*)d_in[6];
    const float* Wp = (const float*)d_in[7];
    const float* bp = (const float*)d_in[8];
    char* ws = (char*)d_ws;
    u16* xb   = (u16*)(ws);
    u16* wqkv = (u16*)(ws + 16777216);
    u16* wpb  = (u16*)(ws + 23068672);
    u16* qbuf = (u16*)(ws + 25165824);
    u16* kbuf = (u16*)(ws + 41943040);
    u16* vtb  = (u16*)(ws + 58720256);   // (B,H,D,T) pre-transposed V
    u16* attb = (u16*)(ws + 75497472);

    cast_all<<<12288, 256, 0, stream>>>(x, Wq, Wk, Wv, Wp, xb, wqkv, wpb);
    qkv_gemm<<<1536, 256, 0, stream>>>(xb, wqkv, bq, bk, bv, qbuf, kbuf, vtb);
    attn_kernel<<<1024, 256, 0, stream>>>(qbuf, kbuf, vtb, attb);
    proj_gemm<<<512, 256, 0, stream>>>(attb, wpb, bp, (float*)d_out);
}

// Round 6
// 184.431 us; speedup vs baseline: 1.0803x; 1.0196x over previous
//
#include <hip/hip_runtime.h>
#include <stdint.h>

typedef unsigned short u16;
typedef __attribute__((ext_vector_type(8))) __bf16 bf16x8;
typedef __attribute__((ext_vector_type(8))) short short8;
typedef __attribute__((ext_vector_type(4))) float f32x4;
typedef __attribute__((ext_vector_type(16))) float f32x16;
typedef __attribute__((ext_vector_type(4))) uint32_t u32x4;

#define AS1 __attribute__((address_space(1)))
#define AS3 __attribute__((address_space(3)))

__device__ __forceinline__ void load_lds16(const void* g, void* l) {
    __builtin_amdgcn_global_load_lds((AS1 void*)g, (AS3 void*)l, 16, 0, 0);
}

__device__ __forceinline__ u16 f2bf(float f) {
    uint32_t u = __builtin_bit_cast(uint32_t, f);
    u += 0x7FFFu + ((u >> 16) & 1u);
    return (u16)(u >> 16);
}

__device__ __forceinline__ f32x4 mfma16(bf16x8 a, bf16x8 b, f32x4 c) {
    return __builtin_amdgcn_mfma_f32_16x16x32_bf16(a, b, c, 0, 0, 0);
}
__device__ __forceinline__ f32x16 mfma32(bf16x8 a, bf16x8 b, f32x16 c) {
    return __builtin_amdgcn_mfma_f32_32x32x16_bf16(a, b, c, 0, 0, 0);
}

// balanced max over an f32x16, written as nested fmax triples so clang can
// fuse to v_max3_f32 (~8 issue slots, depth 4). Pressure-neutral.
__device__ __forceinline__ float max16(const f32x16& s) {
    const float a0 = fmaxf(fmaxf(s[0], s[1]), s[2]);
    const float a1 = fmaxf(fmaxf(s[3], s[4]), s[5]);
    const float a2 = fmaxf(fmaxf(s[6], s[7]), s[8]);
    const float a3 = fmaxf(fmaxf(s[9], s[10]), s[11]);
    const float a4 = fmaxf(fmaxf(s[12], s[13]), s[14]);
    const float b0 = fmaxf(fmaxf(a0, a1), a2);
    const float b1 = fmaxf(fmaxf(a3, a4), s[15]);
    return fmaxf(b0, b1);
}

// ---------------------------------------------------------------- fused cast f32->bf16
// Single launch for x + 4 weight matrices. All ranges are exact multiples of
// 1024 elems/block so no bounds checks needed.
__global__ __launch_bounds__(256) void cast_all(const float* __restrict__ x,
                                                const float* __restrict__ wq,
                                                const float* __restrict__ wk,
                                                const float* __restrict__ wv,
                                                const float* __restrict__ wp,
                                                u16* __restrict__ xb,
                                                u16* __restrict__ wqkv,
                                                u16* __restrict__ wpb) {
    const int bid = blockIdx.x;
    const float* src;
    u16* dst;
    int boff;
    if (bid < 8192)       { src = x;  dst = xb;             boff = bid; }
    else if (bid < 9216)  { src = wq; dst = wqkv;           boff = bid - 8192; }
    else if (bid < 10240) { src = wk; dst = wqkv + 1048576; boff = bid - 9216; }
    else if (bid < 11264) { src = wv; dst = wqkv + 2097152; boff = bid - 10240; }
    else                  { src = wp; dst = wpb;            boff = bid - 11264; }
    const int i = (boff * 256 + threadIdx.x) * 4;
    const float4 v = *(const float4*)(src + i);
    u16 o0 = f2bf(v.x), o1 = f2bf(v.y), o2 = f2bf(v.z), o3 = f2bf(v.w);
    uint32_t lo = (uint32_t)o0 | ((uint32_t)o1 << 16);
    uint32_t hi = (uint32_t)o2 | ((uint32_t)o3 << 16);
    uint2 p; p.x = lo; p.y = hi;
    *(uint2*)(dst + i) = p;
}

// ---------------------------------------------------------------- 128x128 GEMM core
template<int KDIM>
__device__ __forceinline__ void gemm_core(const u16* __restrict__ A, const u16* __restrict__ Bw,
                                          int m0, int n0, char* lds, f32x4 acc[4][4]) {
    const int tid = threadIdx.x;
    const int w = tid >> 6, l = tid & 63;
    const int lg = l >> 4, lc = l & 15;
    const int wm = (w >> 1) * 64, wn = (w & 1) * 64;
    char* As = lds;
    char* Bs = lds + 16384;
    for (int kt = 0; kt < KDIM; kt += 64) {
#pragma unroll
        for (int i = 0; i < 4; ++i) {
            const int e = i * 256 + tid;
            const int row = e >> 3, c = e & 7;
            const int cs = c ^ (row & 7);
            load_lds16(A + (size_t)(m0 + row) * KDIM + kt + cs * 8, As + i * 4096 + w * 1024);
            load_lds16(Bw + (size_t)(n0 + row) * KDIM + kt + cs * 8, Bs + i * 4096 + w * 1024);
        }
        __syncthreads();
#pragma unroll
        for (int kk = 0; kk < 2; ++kk) {
            bf16x8 af[4], bfr[4];
            const int byo = kk * 64 + lg * 16;
#pragma unroll
            for (int mi = 0; mi < 4; ++mi) {
                const int row = wm + mi * 16 + lc;
                af[mi] = *(const bf16x8*)(As + row * 128 + (byo ^ ((row & 7) << 4)));
            }
#pragma unroll
            for (int ni = 0; ni < 4; ++ni) {
                const int row = wn + ni * 16 + lc;
                bfr[ni] = *(const bf16x8*)(Bs + row * 128 + (byo ^ ((row & 7) << 4)));
            }
#pragma unroll
            for (int mi = 0; mi < 4; ++mi)
#pragma unroll
                for (int ni = 0; ni < 4; ++ni)
                    acc[mi][ni] = mfma16(af[mi], bfr[ni], acc[mi][ni]);
        }
        __syncthreads();
    }
}

// ---------------------------------------------------------------- fused QKV projection
__global__ __launch_bounds__(256) void qkv_gemm(const u16* __restrict__ xb, const u16* __restrict__ wqkv,
                                                const float* __restrict__ bq, const float* __restrict__ bk,
                                                const float* __restrict__ bv,
                                                u16* __restrict__ qo, u16* __restrict__ ko, u16* __restrict__ vt) {
    __shared__ char lds[32768];
    f32x4 acc[4][4] = {};
    const int id = blockIdx.x;
    const int xcd = id & 7, sl = id >> 3;
    const int nIdx = sl >> 3, mloc = sl & 7;
    const int m0 = (xcd * 8 + mloc) * 128;
    const int n0 = nIdx * 128;
    gemm_core<1024>(xb, wqkv, m0, n0, lds, acc);
    const int which = n0 >> 10;
    const float* bias = which == 0 ? bq : (which == 1 ? bk : bv);
    const int tid = threadIdx.x;
    const int w = tid >> 6, l = tid & 63;
    const int lg = l >> 4, lc = l & 15;
    const int wm = (w >> 1) * 64, wn = (w & 1) * 64;
    if (which == 2) {
        // V: transposed store. t0 = m0+wm+mi*16+lg*4, 4 consecutive t per (mi,ni).
#pragma unroll
        for (int mi = 0; mi < 4; ++mi)
#pragma unroll
            for (int ni = 0; ni < 4; ++ni) {
                const int ng = n0 + wn + ni * 16 + lc;
                const int c = ng & 1023;
                const int h = c >> 6, d = c & 63;
                const float bb = bias[c];
                const int t0 = m0 + wm + mi * 16 + lg * 4;
                const int b = t0 >> 11, t = t0 & 2047;
                uint32_t w0 = (uint32_t)f2bf(acc[mi][ni][0] + bb) | ((uint32_t)f2bf(acc[mi][ni][1] + bb) << 16);
                uint32_t w1 = (uint32_t)f2bf(acc[mi][ni][2] + bb) | ((uint32_t)f2bf(acc[mi][ni][3] + bb) << 16);
                uint2 pk; pk.x = w0; pk.y = w1;
                *(uint2*)(vt + (((size_t)(b * 16 + h)) * 64 + d) * 2048 + t) = pk;
            }
    } else {
        u16* outb = which == 0 ? qo : ko;
#pragma unroll
        for (int mi = 0; mi < 4; ++mi)
#pragma unroll
            for (int ni = 0; ni < 4; ++ni)
#pragma unroll
                for (int r = 0; r < 4; ++r) {
                    const int m = m0 + wm + mi * 16 + lg * 4 + r;
                    const int ng = n0 + wn + ni * 16 + lc;
                    const int c = ng & 1023;
                    const float v = acc[mi][ni][r] + bias[c];
                    const int h = c >> 6, d = c & 63;
                    const int b = m >> 11, t = m & 2047;
                    outb[(((size_t)(b * 16 + h)) * 2048 + t) * 64 + d] = f2bf(v);
                }
    }
}

// ---------------------------------------------------------------- flash attention (causal)
// 32x32 swapped-QK^T (r0-verified compute & shuffle paths). One block = one
// 128-row q-strip, all 4 waves on it. CU-BALANCED placement: co-resident slots
// on a CU are {s,s+32,s+64,s+96}; strip = (slot&15) ^ mask[k] with mask
// {0,15,5,10} makes every CU's four strip durations sum to 68 tile-units.
// r6 vs r4 (the 188us base):
//  - lrun cross-half add DEFERRED to epilogue (1 shfl_xor per 32-block removed;
//    valid because corr is provably equal across the (l31,l31+32) pair: tm is
//    cross-half-maxed BEFORE the vote, mrun equal by induction)
//  - pairwise rs reduction (dep chain 16 -> 4)
//  - max16 as max3-fusable fmax triples
// permlane32_swap: ABANDONED (r1/r2/r5 evidence: intrinsic path performs no
// cross-lane exchange on this ROCm build; do not retry).
#define CLOG 0.18033688f   /* 0.125 * log2(e) */
__global__ __launch_bounds__(256) __attribute__((amdgpu_waves_per_eu(4, 4)))
void attn_kernel(const u16* __restrict__ qbuf, const u16* __restrict__ kbuf,
                 const u16* __restrict__ vtb, u16* __restrict__ attb) {
    __shared__ char lds[32768];  // [parity][ K 8KB | Vt 8KB ]: K rows [64 s][128B swz],
                                 // Vt rows [64 d][128B swz] (d-major, t within row)
    const int tid = threadIdx.x;
    const int w = tid >> 6, l = tid & 63;
    const int l31 = l & 31, hi = l >> 5;
    const int id = blockIdx.x;
    const int xcd = id & 7, slot = id >> 3;
    const int bh = xcd * 8 + (slot >> 4);        // 8 heads/XCD
    const int sl4 = slot & 15;
    const int kq = slot >> 5;                    // CU-round index, 0..3
    const int mask4[4] = {0, 15, 5, 10};
    const int strip = sl4 ^ mask4[kq];           // per-CU quadruple sums to 30
    const size_t base = (size_t)bh * 2048 * 64;  // same stride for (B,H,T,D)/(B,H,D,T)
    const int qw0 = strip * 128 + w * 32;        // this wave's 32 q rows
    const int jmax = (qw0 + 31) >> 6;            // last KV tile this wave needs
    const int tH = 2 * strip + 2;                // tiles staged by the block
    const int qg = qw0 + l31;

    // Q B-fragments: lane holds q=qw0+l31, d=16t+8hi+j
    bf16x8 aqf[4];
#pragma unroll
    for (int t = 0; t < 4; ++t)
        aqf[t] = *(const bf16x8*)(qbuf + base + (size_t)(qw0 + l31) * 64 + t * 16 + hi * 8);

    f32x16 oacc[2];
#pragma unroll
    for (int i = 0; i < 16; ++i) { oacc[0][i] = 0.f; oacc[1][i] = 0.f; }
    float mrun = -3.0e38f, lrun = 0.f;   // lrun holds OWN-HALF sums (cross-half add deferred)

    // K tile j: rows s=j*64+row (row 0..63), 8x16B chunks, pre-swizzled source.
#define ISSUE_K(J, BUF)                                                                          \
    {                                                                                            \
        _Pragma("unroll")                                                                        \
        for (int i = 0; i < 2; ++i) {                                                            \
            const int e = i * 256 + tid;                                                         \
            const int row = e >> 3, c = e & 7;                                                   \
            const int cs = c ^ (row & 7);                                                        \
            load_lds16(kbuf + base + (size_t)((J) * 64 + row) * 64 + cs * 8,                     \
                       (BUF) + i * 4096 + w * 1024);                                             \
        }                                                                                        \
    }
    // Vt tile j: rows d=row (0..63), t-span j*64..j*64+63, pre-swizzled source.
#define ISSUE_VT(J, BUF)                                                                         \
    {                                                                                            \
        _Pragma("unroll")                                                                        \
        for (int i = 0; i < 2; ++i) {                                                            \
            const int e = i * 256 + tid;                                                         \
            const int row = e >> 3, c = e & 7;                                                   \
            const int cs = c ^ (row & 7);                                                        \
            load_lds16(vtb + base + (size_t)row * 2048 + (J) * 64 + cs * 8,                      \
                       (BUF) + i * 4096 + w * 1024);                                             \
        }                                                                                        \
    }

    ISSUE_K(0, lds);
    ISSUE_VT(0, lds + 8192);
    for (int j = 0; j < tH; ++j) {
        __syncthreads();   // drains tile-j loads; protects buffers from prior compute
        if (j + 1 < tH) {
            char* nb2 = lds + ((j + 1) & 1) * 16384;
            ISSUE_K(j + 1, nb2);
            ISSUE_VT(j + 1, nb2 + 8192);
        }
        if (j <= jmax) {
            char* Ks = lds + (j & 1) * 16384;
            char* Vt = Ks + 8192;
#pragma unroll
            for (int b2 = 0; b2 < 2; ++b2) {
                const int S0b = j * 64 + b2 * 32;
                if (S0b > qw0 + 31) continue;           // fully masked (wave-uniform)
                const bool domask = (S0b + 31 > qw0);
                // ---- S^T = K Q^T for this 32-s block
                f32x16 sf;
#pragma unroll
                for (int i = 0; i < 16; ++i) sf[i] = 0.f;
                const int row = b2 * 32 + l31;
                __builtin_amdgcn_s_setprio(1);
#pragma unroll
                for (int t = 0; t < 4; ++t) {
                    const bf16x8 akf = *(const bf16x8*)(Ks + row * 128 + ((t * 32 + hi * 16) ^ ((row & 7) << 4)));
                    sf = mfma32(akf, aqf[t], sf);
                }
                __builtin_amdgcn_s_setprio(0);
                // ---- causal mask; s row = S0b + (rg&3)+8*(rg>>2)+4*hi
                if (domask) {
#pragma unroll
                    for (int rg = 0; rg < 16; ++rg) {
                        const int ss = S0b + (rg & 3) + 8 * (rg >> 2) + 4 * hi;
                        if (ss > qg) sf[rg] = -3.0e38f;
                    }
                }
                // ---- row max (max3 tree + cross-half) + defer-max
                float tm = max16(sf);
                tm = fmaxf(tm, __shfl_xor(tm, 32, 64));
                const float tmL = tm * CLOG;
                if (!__all(tmL <= mrun + 9.0f)) {       // rare path
                    const float mnew = fmaxf(mrun, tmL);
                    const float corr = exp2f(mrun - mnew);
                    mrun = mnew;
                    lrun *= corr;                        // corr equal across half-pair
#pragma unroll
                    for (int rq = 0; rq < 4; ++rq)
#pragma unroll
                        for (int rr = 0; rr < 4; ++rr) {
                            const int q = rr + 8 * rq + 4 * hi;
                            const float cb = __shfl(corr, q | (l & 32), 64);
                            oacc[0][rq * 4 + rr] *= cb;
                            oacc[1][rq * 4 + rr] *= cb;
                        }
                }
                // ---- P = exp2(raw*CLOG - mrun), own-half row sum (pairwise tree)
                float ps[8];
#pragma unroll
                for (int i = 0; i < 8; ++i) {
                    const float p0 = exp2f(fmaf(sf[2 * i], CLOG, -mrun));
                    const float p1 = exp2f(fmaf(sf[2 * i + 1], CLOG, -mrun));
                    sf[2 * i] = p0;
                    sf[2 * i + 1] = p1;
                    ps[i] = p0 + p1;
                }
                const float q0 = (ps[0] + ps[1]) + (ps[2] + ps[3]);
                const float q1 = (ps[4] + ps[5]) + (ps[6] + ps[7]);
                lrun += q0 + q1;                         // cross-half add deferred
                // ---- pack P pairs: wv[i] = {rg=2i lo, rg=2i+1 hi}
                uint32_t wv[8];
#pragma unroll
                for (int i = 0; i < 8; ++i) {
                    uint32_t ww;
                    asm("v_cvt_pk_bf16_f32 %0, %1, %2" : "=v"(ww) : "v"(sf[2 * i]), "v"(sf[2 * i + 1]));
                    wv[i] = ww;
                }
                // ---- per-ks A-fragment build + PV (r0-verified shuffle/select)
#pragma unroll
                for (int kl = 0; kl < 2; ++kl) {
                    const uint32_t wa = wv[4 * kl + 0], wb_ = wv[4 * kl + 1];
                    const uint32_t wc = wv[4 * kl + 2], wd = wv[4 * kl + 3];
                    const uint32_t xa = (uint32_t)__shfl_xor((int)wa, 32, 64);
                    const uint32_t xb = (uint32_t)__shfl_xor((int)wb_, 32, 64);
                    const uint32_t xc = (uint32_t)__shfl_xor((int)wc, 32, 64);
                    const uint32_t xd = (uint32_t)__shfl_xor((int)wd, 32, 64);
                    u32x4 pw;
                    pw[0] = hi ? xc : wa;
                    pw[1] = hi ? xd : wb_;
                    pw[2] = hi ? wc : xa;
                    pw[3] = hi ? wd : xb;
                    const bf16x8 paf = __builtin_bit_cast(bf16x8, pw);
                    const int ks = b2 * 2 + kl;
                    __builtin_amdgcn_s_setprio(1);
#pragma unroll
                    for (int nb = 0; nb < 2; ++nb) {
                        const int vrow = nb * 32 + l31;
                        const bf16x8 bvf = *(const bf16x8*)(Vt + vrow * 128 +
                            ((ks * 32 + hi * 16) ^ ((vrow & 7) << 4)));
                        oacc[nb] = mfma32(paf, bvf, oacc[nb]);
                    }
                    __builtin_amdgcn_s_setprio(0);
                }
            }
        }
    }
    // ---- epilogue: cross-half lrun, normalize, write (B,T,C) bf16
    const int b = bh >> 4, h = bh & 15;
    const float lfull = lrun + __shfl_xor(lrun, 32, 64);
    const float inv = 1.f / lfull;
#pragma unroll
    for (int rq = 0; rq < 4; ++rq)
#pragma unroll
        for (int rr = 0; rr < 4; ++rr) {
            const int q = rr + 8 * rq + 4 * hi;
            const float iv = __shfl(inv, q | (l & 32), 64);
            const int t = qw0 + q;
#pragma unroll
            for (int nb = 0; nb < 2; ++nb) {
                const int c = h * 64 + nb * 32 + l31;
                attb[((size_t)(b * 2048 + t)) * 1024 + c] = f2bf(oacc[nb][rq * 4 + rr] * iv);
            }
        }
}

// ---------------------------------------------------------------- output projection (fp32 out)
__global__ __launch_bounds__(256) void proj_gemm(const u16* __restrict__ attb, const u16* __restrict__ wpb,
                                                 const float* __restrict__ bp, float* __restrict__ out) {
    __shared__ char lds[32768];
    f32x4 acc[4][4] = {};
    const int id = blockIdx.x;
    const int xcd = id & 7, sl = id >> 3;
    const int nIdx = sl >> 3, mloc = sl & 7;
    const int m0 = (xcd * 8 + mloc) * 128;
    const int n0 = nIdx * 128;
    gemm_core<1024>(attb, wpb, m0, n0, lds, acc);
    const int tid = threadIdx.x;
    const int w = tid >> 6, l = tid & 63;
    const int lg = l >> 4, lc = l & 15;
    const int wm = (w >> 1) * 64, wn = (w & 1) * 64;
#pragma unroll
    for (int mi = 0; mi < 4; ++mi)
#pragma unroll
        for (int ni = 0; ni < 4; ++ni)
#pragma unroll
            for (int r = 0; r < 4; ++r) {
                const int m = m0 + wm + mi * 16 + lg * 4 + r;
                const int n = n0 + wn + ni * 16 + lc;
                out[(size_t)m * 1024 + n] = acc[mi][ni][r] + bp[n];
            }
}

// ---------------------------------------------------------------- launch
extern "C" void kernel_launch(void* const* d_in, const int* in_sizes, int n_in,
                              void* d_out, int out_size, void* d_ws, size_t ws_size,
                              hipStream_t stream) {
    const float* x  = (const float*)d_in[0];
    const float* Wk = (const float*)d_in[1];
    const float* bk = (const float*)d_in[2];
    const float* Wq = (const float*)d_in[3];
    const float* bq = (const float*)d_in[4];
    const float* Wv = (const float*)d_in[5];
    const float* bv = (const float*)d_in[6];
    const float* Wp = (const float*)d_in[7];
    const float* bp = (const float*)d_in[8];
    char* ws = (char*)d_ws;
    u16* xb   = (u16*)(ws);
    u16* wqkv = (u16*)(ws + 16777216);
    u16* wpb  = (u16*)(ws + 23068672);
    u16* qbuf = (u16*)(ws + 25165824);
    u16* kbuf = (u16*)(ws + 41943040);
    u16* vtb  = (u16*)(ws + 58720256);   // (B,H,D,T) pre-transposed V
    u16* attb = (u16*)(ws + 75497472);

    cast_all<<<12288, 256, 0, stream>>>(x, Wq, Wk, Wv, Wp, xb, wqkv, wpb);
    qkv_gemm<<<1536, 256, 0, stream>>>(xb, wqkv, bq, bk, bv, qbuf, kbuf, vtb);
    attn_kernel<<<1024, 256, 0, stream>>>(qbuf, kbuf, vtb, attb);
    proj_gemm<<<512, 256, 0, stream>>>(attb, wpb, bp, (float*)d_out);
}

// Round 7
// 183.295 us; speedup vs baseline: 1.0869x; 1.0062x over previous
//
#include <hip/hip_runtime.h>
#include <stdint.h>

typedef unsigned short u16;
typedef __attribute__((ext_vector_type(8))) __bf16 bf16x8;
typedef __attribute__((ext_vector_type(8))) short short8;
typedef __attribute__((ext_vector_type(4))) float f32x4;
typedef __attribute__((ext_vector_type(16))) float f32x16;
typedef __attribute__((ext_vector_type(4))) uint32_t u32x4;

#define AS1 __attribute__((address_space(1)))
#define AS3 __attribute__((address_space(3)))

__device__ __forceinline__ void load_lds16(const void* g, void* l) {
    __builtin_amdgcn_global_load_lds((AS1 void*)g, (AS3 void*)l, 16, 0, 0);
}

__device__ __forceinline__ u16 f2bf(float f) {
    uint32_t u = __builtin_bit_cast(uint32_t, f);
    u += 0x7FFFu + ((u >> 16) & 1u);
    return (u16)(u >> 16);
}

__device__ __forceinline__ f32x4 mfma16(bf16x8 a, bf16x8 b, f32x4 c) {
    return __builtin_amdgcn_mfma_f32_16x16x32_bf16(a, b, c, 0, 0, 0);
}
__device__ __forceinline__ f32x16 mfma32(bf16x8 a, bf16x8 b, f32x16 c) {
    return __builtin_amdgcn_mfma_f32_32x32x16_bf16(a, b, c, 0, 0, 0);
}

// balanced max over an f32x16, written as nested fmax triples so clang can
// fuse to v_max3_f32 (~8 issue slots, depth 4). Pressure-neutral.
__device__ __forceinline__ float max16(const f32x16& s) {
    const float a0 = fmaxf(fmaxf(s[0], s[1]), s[2]);
    const float a1 = fmaxf(fmaxf(s[3], s[4]), s[5]);
    const float a2 = fmaxf(fmaxf(s[6], s[7]), s[8]);
    const float a3 = fmaxf(fmaxf(s[9], s[10]), s[11]);
    const float a4 = fmaxf(fmaxf(s[12], s[13]), s[14]);
    const float b0 = fmaxf(fmaxf(a0, a1), a2);
    const float b1 = fmaxf(fmaxf(a3, a4), s[15]);
    return fmaxf(b0, b1);
}

__device__ __forceinline__ float rcpf(float x) {
    float r;
    asm("v_rcp_f32 %0, %1" : "=v"(r) : "v"(x));
    return r;
}

// ---------------------------------------------------------------- fused cast f32->bf16
// Single launch for x + 4 weight matrices. All ranges are exact multiples of
// 1024 elems/block so no bounds checks needed.
__global__ __launch_bounds__(256) void cast_all(const float* __restrict__ x,
                                                const float* __restrict__ wq,
                                                const float* __restrict__ wk,
                                                const float* __restrict__ wv,
                                                const float* __restrict__ wp,
                                                u16* __restrict__ xb,
                                                u16* __restrict__ wqkv,
                                                u16* __restrict__ wpb) {
    const int bid = blockIdx.x;
    const float* src;
    u16* dst;
    int boff;
    if (bid < 8192)       { src = x;  dst = xb;             boff = bid; }
    else if (bid < 9216)  { src = wq; dst = wqkv;           boff = bid - 8192; }
    else if (bid < 10240) { src = wk; dst = wqkv + 1048576; boff = bid - 9216; }
    else if (bid < 11264) { src = wv; dst = wqkv + 2097152; boff = bid - 10240; }
    else                  { src = wp; dst = wpb;            boff = bid - 11264; }
    const int i = (boff * 256 + threadIdx.x) * 4;
    const float4 v = *(const float4*)(src + i);
    u16 o0 = f2bf(v.x), o1 = f2bf(v.y), o2 = f2bf(v.z), o3 = f2bf(v.w);
    uint32_t lo = (uint32_t)o0 | ((uint32_t)o1 << 16);
    uint32_t hi = (uint32_t)o2 | ((uint32_t)o3 << 16);
    uint2 p; p.x = lo; p.y = hi;
    *(uint2*)(dst + i) = p;
}

// ---------------------------------------------------------------- 128x128 GEMM core
template<int KDIM>
__device__ __forceinline__ void gemm_core(const u16* __restrict__ A, const u16* __restrict__ Bw,
                                          int m0, int n0, char* lds, f32x4 acc[4][4]) {
    const int tid = threadIdx.x;
    const int w = tid >> 6, l = tid & 63;
    const int lg = l >> 4, lc = l & 15;
    const int wm = (w >> 1) * 64, wn = (w & 1) * 64;
    char* As = lds;
    char* Bs = lds + 16384;
    for (int kt = 0; kt < KDIM; kt += 64) {
#pragma unroll
        for (int i = 0; i < 4; ++i) {
            const int e = i * 256 + tid;
            const int row = e >> 3, c = e & 7;
            const int cs = c ^ (row & 7);
            load_lds16(A + (size_t)(m0 + row) * KDIM + kt + cs * 8, As + i * 4096 + w * 1024);
            load_lds16(Bw + (size_t)(n0 + row) * KDIM + kt + cs * 8, Bs + i * 4096 + w * 1024);
        }
        __syncthreads();
#pragma unroll
        for (int kk = 0; kk < 2; ++kk) {
            bf16x8 af[4], bfr[4];
            const int byo = kk * 64 + lg * 16;
#pragma unroll
            for (int mi = 0; mi < 4; ++mi) {
                const int row = wm + mi * 16 + lc;
                af[mi] = *(const bf16x8*)(As + row * 128 + (byo ^ ((row & 7) << 4)));
            }
#pragma unroll
            for (int ni = 0; ni < 4; ++ni) {
                const int row = wn + ni * 16 + lc;
                bfr[ni] = *(const bf16x8*)(Bs + row * 128 + (byo ^ ((row & 7) << 4)));
            }
#pragma unroll
            for (int mi = 0; mi < 4; ++mi)
#pragma unroll
                for (int ni = 0; ni < 4; ++ni)
                    acc[mi][ni] = mfma16(af[mi], bfr[ni], acc[mi][ni]);
        }
        __syncthreads();
    }
}

// ---------------------------------------------------------------- fused QKV projection
__global__ __launch_bounds__(256) void qkv_gemm(const u16* __restrict__ xb, const u16* __restrict__ wqkv,
                                                const float* __restrict__ bq, const float* __restrict__ bk,
                                                const float* __restrict__ bv,
                                                u16* __restrict__ qo, u16* __restrict__ ko, u16* __restrict__ vt) {
    __shared__ char lds[32768];
    f32x4 acc[4][4] = {};
    const int id = blockIdx.x;
    const int xcd = id & 7, sl = id >> 3;
    const int nIdx = sl >> 3, mloc = sl & 7;
    const int m0 = (xcd * 8 + mloc) * 128;
    const int n0 = nIdx * 128;
    gemm_core<1024>(xb, wqkv, m0, n0, lds, acc);
    const int which = n0 >> 10;
    const float* bias = which == 0 ? bq : (which == 1 ? bk : bv);
    const int tid = threadIdx.x;
    const int w = tid >> 6, l = tid & 63;
    const int lg = l >> 4, lc = l & 15;
    const int wm = (w >> 1) * 64, wn = (w & 1) * 64;
    if (which == 2) {
        // V: transposed store. t0 = m0+wm+mi*16+lg*4, 4 consecutive t per (mi,ni).
#pragma unroll
        for (int mi = 0; mi < 4; ++mi)
#pragma unroll
            for (int ni = 0; ni < 4; ++ni) {
                const int ng = n0 + wn + ni * 16 + lc;
                const int c = ng & 1023;
                const int h = c >> 6, d = c & 63;
                const float bb = bias[c];
                const int t0 = m0 + wm + mi * 16 + lg * 4;
                const int b = t0 >> 11, t = t0 & 2047;
                uint32_t w0 = (uint32_t)f2bf(acc[mi][ni][0] + bb) | ((uint32_t)f2bf(acc[mi][ni][1] + bb) << 16);
                uint32_t w1 = (uint32_t)f2bf(acc[mi][ni][2] + bb) | ((uint32_t)f2bf(acc[mi][ni][3] + bb) << 16);
                uint2 pk; pk.x = w0; pk.y = w1;
                *(uint2*)(vt + (((size_t)(b * 16 + h)) * 64 + d) * 2048 + t) = pk;
            }
    } else {
        u16* outb = which == 0 ? qo : ko;
#pragma unroll
        for (int mi = 0; mi < 4; ++mi)
#pragma unroll
            for (int ni = 0; ni < 4; ++ni)
#pragma unroll
                for (int r = 0; r < 4; ++r) {
                    const int m = m0 + wm + mi * 16 + lg * 4 + r;
                    const int ng = n0 + wn + ni * 16 + lc;
                    const int c = ng & 1023;
                    const float v = acc[mi][ni][r] + bias[c];
                    const int h = c >> 6, d = c & 63;
                    const int b = m >> 11, t = m & 2047;
                    outb[(((size_t)(b * 16 + h)) * 2048 + t) * 64 + d] = f2bf(v);
                }
    }
}

// ---------------------------------------------------------------- flash attention (causal)
// 32x32 swapped-QK^T. One block = one 128-row q-strip, all 4 waves on it.
// CU-BALANCED placement: strip = (slot&15) ^ mask[slot>>5].
// r7 vs r6: merged 64-s softmax per tile -- r3-verified MATH (r3 passed; it only
// spilled), restructured for register pressure:
//  - single wv[8] reused across both 32-blocks (r3 held wv0+wv1)
//  - PV of block 0 issued BEFORE block 1's exp/pack (sf0/wv die early)
//  - one max-bperm + one vote per 64-s tile (was per 32-s block)
//  - hoisted QKT of block 1 gives independent MFMA work under softmax-0 latency
// permlane32_swap: ABANDONED (r1/r2/r5: no cross-lane exchange on this build).
#define CLOG 0.18033688f   /* 0.125 * log2(e) */
__global__ __launch_bounds__(256) __attribute__((amdgpu_waves_per_eu(4, 4)))
void attn_kernel(const u16* __restrict__ qbuf, const u16* __restrict__ kbuf,
                 const u16* __restrict__ vtb, u16* __restrict__ attb) {
    __shared__ char lds[32768];  // [parity][ K 8KB | Vt 8KB ]: K rows [64 s][128B swz],
                                 // Vt rows [64 d][128B swz] (d-major, t within row)
    const int tid = threadIdx.x;
    const int w = tid >> 6, l = tid & 63;
    const int l31 = l & 31, hi = l >> 5;
    const int id = blockIdx.x;
    const int xcd = id & 7, slot = id >> 3;
    const int bh = xcd * 8 + (slot >> 4);        // 8 heads/XCD
    const int sl4 = slot & 15;
    const int kq = slot >> 5;                    // CU-round index, 0..3
    const int mask4[4] = {0, 15, 5, 10};
    const int strip = sl4 ^ mask4[kq];           // per-CU quadruple sums to 30
    const size_t base = (size_t)bh * 2048 * 64;  // same stride for (B,H,T,D)/(B,H,D,T)
    const int qw0 = strip * 128 + w * 32;        // this wave's 32 q rows
    const int jmax = (qw0 + 31) >> 6;            // last KV tile this wave needs
    const int tH = 2 * strip + 2;                // tiles staged by the block
    const int qg = qw0 + l31;

    // Q B-fragments: lane holds q=qw0+l31, d=16t+8hi+j
    bf16x8 aqf[4];
#pragma unroll
    for (int t = 0; t < 4; ++t)
        aqf[t] = *(const bf16x8*)(qbuf + base + (size_t)(qw0 + l31) * 64 + t * 16 + hi * 8);

    f32x16 oacc[2];
#pragma unroll
    for (int i = 0; i < 16; ++i) { oacc[0][i] = 0.f; oacc[1][i] = 0.f; }
    float mrun = -3.0e38f, lrun = 0.f;   // lrun holds OWN-HALF sums (cross-half add deferred)

    // K tile j: rows s=j*64+row (row 0..63), 8x16B chunks, pre-swizzled source.
#define ISSUE_K(J, BUF)                                                                          \
    {                                                                                            \
        _Pragma("unroll")                                                                        \
        for (int i = 0; i < 2; ++i) {                                                            \
            const int e = i * 256 + tid;                                                         \
            const int row = e >> 3, c = e & 7;                                                   \
            const int cs = c ^ (row & 7);                                                        \
            load_lds16(kbuf + base + (size_t)((J) * 64 + row) * 64 + cs * 8,                     \
                       (BUF) + i * 4096 + w * 1024);                                             \
        }                                                                                        \
    }
    // Vt tile j: rows d=row (0..63), t-span j*64..j*64+63, pre-swizzled source.
#define ISSUE_VT(J, BUF)                                                                         \
    {                                                                                            \
        _Pragma("unroll")                                                                        \
        for (int i = 0; i < 2; ++i) {                                                            \
            const int e = i * 256 + tid;                                                         \
            const int row = e >> 3, c = e & 7;                                                   \
            const int cs = c ^ (row & 7);                                                        \
            load_lds16(vtb + base + (size_t)row * 2048 + (J) * 64 + cs * 8,                      \
                       (BUF) + i * 4096 + w * 1024);                                             \
        }                                                                                        \
    }

// PV step for one 32-wide k-slot group (r0-verified shuffle/select build).
#define PVSTEP(W, KL, KS)                                                       \
    {                                                                           \
        const uint32_t wa = W[4 * (KL) + 0], wb_ = W[4 * (KL) + 1];             \
        const uint32_t wc = W[4 * (KL) + 2], wd = W[4 * (KL) + 3];              \
        const uint32_t xa = (uint32_t)__shfl_xor((int)wa, 32, 64);              \
        const uint32_t xb = (uint32_t)__shfl_xor((int)wb_, 32, 64);             \
        const uint32_t xc = (uint32_t)__shfl_xor((int)wc, 32, 64);              \
        const uint32_t xd = (uint32_t)__shfl_xor((int)wd, 32, 64);              \
        u32x4 pw;                                                               \
        pw[0] = hi ? xc : wa;                                                   \
        pw[1] = hi ? xd : wb_;                                                  \
        pw[2] = hi ? wc : xa;                                                   \
        pw[3] = hi ? wd : xb;                                                   \
        const bf16x8 paf = __builtin_bit_cast(bf16x8, pw);                      \
        __builtin_amdgcn_s_setprio(1);                                          \
        _Pragma("unroll")                                                       \
        for (int nb = 0; nb < 2; ++nb) {                                        \
            const int vrow = nb * 32 + l31;                                     \
            const bf16x8 bvf = *(const bf16x8*)(Vt + vrow * 128 +               \
                (((KS) * 32 + hi * 16) ^ ((vrow & 7) << 4)));                   \
            oacc[nb] = mfma32(paf, bvf, oacc[nb]);                              \
        }                                                                       \
        __builtin_amdgcn_s_setprio(0);                                          \
    }

// exp + own-half pairwise sum + pack for one sf block (sf consumed, wv filled)
#define SOFTMAX_PACK(SF, WV)                                                    \
    {                                                                           \
        float ps[8];                                                            \
        _Pragma("unroll")                                                       \
        for (int i = 0; i < 8; ++i) {                                           \
            const float p0 = exp2f(fmaf((SF)[2 * i], CLOG, -mrun));             \
            const float p1 = exp2f(fmaf((SF)[2 * i + 1], CLOG, -mrun));         \
            (SF)[2 * i] = p0;                                                   \
            (SF)[2 * i + 1] = p1;                                               \
            ps[i] = p0 + p1;                                                    \
        }                                                                       \
        lrun += ((ps[0] + ps[1]) + (ps[2] + ps[3])) +                           \
                ((ps[4] + ps[5]) + (ps[6] + ps[7]));                            \
        _Pragma("unroll")                                                       \
        for (int i = 0; i < 8; ++i) {                                           \
            uint32_t ww;                                                        \
            asm("v_cvt_pk_bf16_f32 %0, %1, %2"                                  \
                : "=v"(ww) : "v"((SF)[2 * i]), "v"((SF)[2 * i + 1]));           \
            (WV)[i] = ww;                                                       \
        }                                                                       \
    }

    ISSUE_K(0, lds);
    ISSUE_VT(0, lds + 8192);
    for (int j = 0; j < tH; ++j) {
        __syncthreads();   // drains tile-j loads; protects buffers from prior compute
        if (j + 1 < tH) {
            char* nb2 = lds + ((j + 1) & 1) * 16384;
            ISSUE_K(j + 1, nb2);
            ISSUE_VT(j + 1, nb2 + 8192);
        }
        if (j <= jmax) {
            char* Ks = lds + (j & 1) * 16384;
            char* Vt = Ks + 8192;
            const bool two = (qw0 >= j * 64 + 32);   // wave-uniform: upper 32-s block live?
            // ---- S^T = K Q^T, block 0 (rows 0..31); block 1 hoisted for ILP
            f32x16 sf0, sf1;
#pragma unroll
            for (int i = 0; i < 16; ++i) sf0[i] = 0.f;
            __builtin_amdgcn_s_setprio(1);
#pragma unroll
            for (int t = 0; t < 4; ++t) {
                const bf16x8 ak = *(const bf16x8*)(Ks + l31 * 128 + ((t * 32 + hi * 16) ^ ((l31 & 7) << 4)));
                sf0 = mfma32(ak, aqf[t], sf0);
            }
            __builtin_amdgcn_s_setprio(0);
            float tm;
            if (two) {
#pragma unroll
                for (int i = 0; i < 16; ++i) sf1[i] = 0.f;
                __builtin_amdgcn_s_setprio(1);
#pragma unroll
                for (int t = 0; t < 4; ++t) {
                    const int row = 32 + l31;
                    const bf16x8 ak = *(const bf16x8*)(Ks + row * 128 + ((t * 32 + hi * 16) ^ ((row & 7) << 4)));
                    sf1 = mfma32(ak, aqf[t], sf1);
                }
                __builtin_amdgcn_s_setprio(0);
                // block0 unmasked when `two`; block1 masked only on the straddle
                if (qw0 == j * 64 + 32) {
#pragma unroll
                    for (int rg = 0; rg < 16; ++rg) {
                        const int ss = j * 64 + 32 + (rg & 3) + 8 * (rg >> 2) + 4 * hi;
                        if (ss > qg) sf1[rg] = -3.0e38f;
                    }
                }
                tm = fmaxf(max16(sf0), max16(sf1));
            } else {
                // diagonal tile start (qw0 == j*64): block 0 only, always masked
#pragma unroll
                for (int rg = 0; rg < 16; ++rg) {
                    const int ss = j * 64 + (rg & 3) + 8 * (rg >> 2) + 4 * hi;
                    if (ss > qg) sf0[rg] = -3.0e38f;
                }
                tm = max16(sf0);
            }
            // ---- ONE cross-half max + ONE defer-max vote per 64-s tile
            tm = fmaxf(tm, __shfl_xor(tm, 32, 64));
            const float tmL = tm * CLOG;
            if (!__all(tmL <= mrun + 9.0f)) {           // rare path
                const float mnew = fmaxf(mrun, tmL);
                const float corr = exp2f(mrun - mnew);
                mrun = mnew;
                lrun *= corr;                            // corr equal across half-pair
#pragma unroll
                for (int rq = 0; rq < 4; ++rq)
#pragma unroll
                    for (int rr = 0; rr < 4; ++rr) {
                        const int q = rr + 8 * rq + 4 * hi;
                        const float cb = __shfl(corr, q | (l & 32), 64);
                        oacc[0][rq * 4 + rr] *= cb;
                        oacc[1][rq * 4 + rr] *= cb;
                    }
            }
            // ---- block 0 finish FIRST (sf0/wv die before block 1's pack peaks)
            uint32_t wv[8];
            SOFTMAX_PACK(sf0, wv)
            PVSTEP(wv, 0, 0)
            PVSTEP(wv, 1, 1)
            if (two) {
                SOFTMAX_PACK(sf1, wv)
                PVSTEP(wv, 0, 2)
                PVSTEP(wv, 1, 3)
            }
        }
    }
    // ---- epilogue: cross-half lrun, normalize (v_rcp), write (B,T,C) bf16
    const int b = bh >> 4, h = bh & 15;
    const float lfull = lrun + __shfl_xor(lrun, 32, 64);
    const float inv = rcpf(lfull);
#pragma unroll
    for (int rq = 0; rq < 4; ++rq)
#pragma unroll
        for (int rr = 0; rr < 4; ++rr) {
            const int q = rr + 8 * rq + 4 * hi;
            const float iv = __shfl(inv, q | (l & 32), 64);
            const int t = qw0 + q;
#pragma unroll
            for (int nb = 0; nb < 2; ++nb) {
                const int c = h * 64 + nb * 32 + l31;
                attb[((size_t)(b * 2048 + t)) * 1024 + c] = f2bf(oacc[nb][rq * 4 + rr] * iv);
            }
        }
}

// ---------------------------------------------------------------- output projection (fp32 out)
__global__ __launch_bounds__(256) void proj_gemm(const u16* __restrict__ attb, const u16* __restrict__ wpb,
                                                 const float* __restrict__ bp, float* __restrict__ out) {
    __shared__ char lds[32768];
    f32x4 acc[4][4] = {};
    const int id = blockIdx.x;
    const int xcd = id & 7, sl = id >> 3;
    const int nIdx = sl >> 3, mloc = sl & 7;
    const int m0 = (xcd * 8 + mloc) * 128;
    const int n0 = nIdx * 128;
    gemm_core<1024>(attb, wpb, m0, n0, lds, acc);
    const int tid = threadIdx.x;
    const int w = tid >> 6, l = tid & 63;
    const int lg = l >> 4, lc = l & 15;
    const int wm = (w >> 1) * 64, wn = (w & 1) * 64;
#pragma unroll
    for (int mi = 0; mi < 4; ++mi)
#pragma unroll
        for (int ni = 0; ni < 4; ++ni)
#pragma unroll
            for (int r = 0; r < 4; ++r) {
                const int m = m0 + wm + mi * 16 + lg * 4 + r;
                const int n = n0 + wn + ni * 16 + lc;
                out[(size_t)m * 1024 + n] = acc[mi][ni][r] + bp[n];
            }
}

// ---------------------------------------------------------------- launch
extern "C" void kernel_launch(void* const* d_in, const int* in_sizes, int n_in,
                              void* d_out, int out_size, void* d_ws, size_t ws_size,
                              hipStream_t stream) {
    const float* x  = (const float*)d_in[0];
    const float* Wk = (const float*)d_in[1];
    const float* bk = (const float*)d_in[2];
    const float* Wq = (const float*)d_in[3];
    const float* bq = (const float*)d_in[4];
    const float* Wv = (const float*)d_in[5];
    const float* bv = (const float*)d_in[6];
    const float* Wp = (const float*)d_in[7];
    const float* bp = (const float*)d_in[8];
    char* ws = (char*)d_ws;
    u16* xb   = (u16*)(ws);
    u16* wqkv = (u16*)(ws + 16777216);
    u16* wpb  = (u16*)(ws + 23068672);
    u16* qbuf = (u16*)(ws + 25165824);
    u16* kbuf = (u16*)(ws + 41943040);
    u16* vtb  = (u16*)(ws + 58720256);   // (B,H,D,T) pre-transposed V
    u16* attb = (u16*)(ws + 75497472);

    cast_all<<<12288, 256, 0, stream>>>(x, Wq, Wk, Wv, Wp, xb, wqkv, wpb);
    qkv_gemm<<<1536, 256, 0, stream>>>(xb, wqkv, bq, bk, bv, qbuf, kbuf, vtb);
    attn_kernel<<<1024, 256, 0, stream>>>(qbuf, kbuf, vtb, attb);
    proj_gemm<<<512, 256, 0, stream>>>(attb, wpb, bp, (float*)d_out);
}